// Round 7
// baseline (203.075 us; speedup 1.0000x reference)
//
#include <hip/hip_runtime.h>
#include <hip/hip_bf16.h>
#include <math.h>

#define NCLS 256
#define PER_CLASS 128
#define NSUP 5
#define NQRY 123              // PER_CLASS - NSUP
#define NVIEW 2
#define DD 384
#define NQ_TOT (NCLS * NQRY)  // 31488
#define NKT 12                // K tiles of 32

typedef __attribute__((ext_vector_type(8))) short short8;
typedef __attribute__((ext_vector_type(4))) float floatx4;

union FragU { uint4 u; short8 s; };
union PkU { __hip_bfloat162 b2; unsigned int u; };

__device__ __forceinline__ unsigned int cvt2bf(float lo, float hi) {
    PkU p;
    p.b2 = __float22bfloat162_rn(make_float2(lo, hi));
    return p.u;
}

// ---------- kernel 1: prototypes -> bf16 + y2, fused (unchanged, verified) ----------
__global__ __launch_bounds__(384) void proto_kernel(const float* __restrict__ reps,
                                                    ushort* __restrict__ pbf,
                                                    float* __restrict__ y2) {
    __shared__ float wp[6];
    const int b = blockIdx.x;          // v*256 + c
    const int c = b & 255, v = b >> 8;
    const int d = threadIdx.x;         // 0..383
    const float* p = reps + ((size_t)(c * PER_CLASS) * NVIEW + v) * DD + d;
    float s = 0.f;
#pragma unroll
    for (int k = 0; k < NSUP; ++k) s += p[(size_t)k * NVIEW * DD];
    s *= 0.2f;
    __hip_bfloat16 h = __float2bfloat16(s);
    pbf[(size_t)b * DD + d] = *reinterpret_cast<ushort*>(&h);
    float q = s * s;
#pragma unroll
    for (int o = 1; o < 64; o <<= 1) q += __shfl_xor(q, o);
    if ((d & 63) == 0) wp[d >> 6] = q;
    __syncthreads();
    if (d == 0) y2[b] = wp[0] + wp[1] + wp[2] + wp[3] + wp[4] + wp[5];
}

// ---------- kernel 2: barrier-free, LDS-free MFMA GEMM + fused logsumexp/NLL ----------
// Each wave independently computes 32 queries x 256 classes (full K):
//   A-frags loaded straight from reps (fp32->bf16 in-reg), B-frags straight from
//   L2-resident pbf (16 contiguous bytes per lane). No staging, no __syncthreads
//   in the K-loop -> compiler emits fine-grained vmcnt, loads pipeline freely.
__global__ __launch_bounds__(256, 2) void main_kernel(const float* __restrict__ reps,
                                                      const ushort* __restrict__ pbf,
                                                      const float* __restrict__ y2g,
                                                      float* __restrict__ out) {
    __shared__ float wred[4];

    const int t = threadIdx.x;
    const int v = blockIdx.y;
    const int wave = t >> 6;
    const int lane = t & 63;
    const int col = lane & 15;   // MFMA m/n index
    const int quad = lane >> 4;  // MFMA k-oct index / C row group
    const int q0w = blockIdx.x * 128 + wave * 32;  // this wave's first query

    // A sources: lane (col) owns query rows q0w+col and q0w+16+col; k-oct = quad*8
    const int r0 = q0w + col;
    const int r1 = q0w + 16 + col;
    const float* a0 = reps +
        (size_t)((r0 / NQRY) * PER_CLASS + NSUP + (r0 % NQRY)) * (NVIEW * DD) + v * DD + quad * 8;
    const float* a1 = reps +
        (size_t)((r1 / NQRY) * PER_CLASS + NSUP + (r1 % NQRY)) * (NVIEW * DD) + v * DD + quad * 8;
    // B source: lane (col,quad) reads pbf[class = nt*16+col][k = kt*32 + quad*8 .. +8)
    const ushort* bb = pbf + (size_t)(v * NCLS + col) * DD + quad * 8;

    floatx4 acc[2][16];
#pragma unroll
    for (int m = 0; m < 2; ++m)
#pragma unroll
        for (int nt = 0; nt < 16; ++nt) acc[m][nt] = (floatx4)0.f;

#pragma unroll
    for (int kt = 0; kt < NKT; ++kt) {
        float4 f0 = *(const float4*)(a0 + kt * 32);
        float4 f1 = *(const float4*)(a0 + kt * 32 + 4);
        float4 g0 = *(const float4*)(a1 + kt * 32);
        float4 g1 = *(const float4*)(a1 + kt * 32 + 4);
        FragU A0, A1;
        A0.u.x = cvt2bf(f0.x, f0.y); A0.u.y = cvt2bf(f0.z, f0.w);
        A0.u.z = cvt2bf(f1.x, f1.y); A0.u.w = cvt2bf(f1.z, f1.w);
        A1.u.x = cvt2bf(g0.x, g0.y); A1.u.y = cvt2bf(g0.z, g0.w);
        A1.u.z = cvt2bf(g1.x, g1.y); A1.u.w = cvt2bf(g1.z, g1.w);
#pragma unroll
        for (int nt = 0; nt < 16; ++nt) {
            FragU B;
            B.u = *(const uint4*)(bb + (size_t)nt * 16 * DD + kt * 32);
            acc[0][nt] = __builtin_amdgcn_mfma_f32_16x16x32_bf16(A0.s, B.s, acc[0][nt], 0, 0, 0);
            acc[1][nt] = __builtin_amdgcn_mfma_f32_16x16x32_bf16(A1.s, B.s, acc[1][nt], 0, 0, 0);
        }
    }

    // ---- epilogue: wave-private logsumexp + NLL over all 256 classes ----
    float y2c[16];
#pragma unroll
    for (int nt = 0; nt < 16; ++nt) y2c[nt] = y2g[v * NCLS + nt * 16 + col];

    float corr = 0.f, lsum = 0.f;
#pragma unroll
    for (int m = 0; m < 2; ++m) {
#pragma unroll
        for (int r = 0; r < 4; ++r) {
            // C layout: query = q0w + m*16 + quad*4 + r, class = nt*16 + col
            const int qn = q0w + m * 16 + quad * 4 + r;
            const int cn = qn / NQRY;
            float s[16];
            float mx = -1e30f;
#pragma unroll
            for (int nt = 0; nt < 16; ++nt) {
                s[nt] = 2.f * acc[m][nt][r] - y2c[nt];
                mx = fmaxf(mx, s[nt]);
                if (cn == nt * 16 + col) corr += s[nt];
            }
#pragma unroll
            for (int o = 1; o < 16; o <<= 1) mx = fmaxf(mx, __shfl_xor(mx, o));
            float e = 0.f;
#pragma unroll
            for (int nt = 0; nt < 16; ++nt) e += __expf(s[nt] - mx);
#pragma unroll
            for (int o = 1; o < 16; o <<= 1) e += __shfl_xor(e, o);
            if (col == 0) lsum += mx + __logf(e);
        }
    }
    float val = lsum - corr;
#pragma unroll
    for (int o = 1; o < 64; o <<= 1) val += __shfl_xor(val, o);
    if (lane == 0) wred[wave] = val;
    __syncthreads();
    if (t == 0)
        atomicAdd(out, (wred[0] + wred[1] + wred[2] + wred[3]) *
                           (1.f / (float)(NQ_TOT * NVIEW)));
}

extern "C" void kernel_launch(void* const* d_in, const int* in_sizes, int n_in,
                              void* d_out, int out_size, void* d_ws, size_t ws_size,
                              hipStream_t stream) {
    const float* reps = (const float*)d_in[0];
    float* ws = (float*)d_ws;
    ushort* pbf = (ushort*)ws;                      // 196608 ushorts
    float* y2 = (float*)(pbf + NVIEW * NCLS * DD);  // 512 floats
    float* out = (float*)d_out;

    hipMemsetAsync(out, 0, sizeof(float), stream);
    proto_kernel<<<dim3(NVIEW * NCLS), dim3(DD), 0, stream>>>(reps, pbf, y2);
    main_kernel<<<dim3(NQ_TOT / 128, NVIEW), dim3(256), 0, stream>>>(reps, pbf, y2, out);
}